// Round 2
// baseline (407.532 us; speedup 1.0000x reference)
//
#include <hip/hip_runtime.h>
#include <hip/hip_bf16.h>
#include <cstdint>
#include <cstddef>

#define DMODEL 1024
#define NHEADS 16
#define HDIM 64
#define BATCH 4
#define SEQ 2048
#define MROWS (BATCH*SEQ)   // 8192
#define N3 (3*DMODEL)       // 3072
#define BHCNT (BATCH*NHEADS) // 64

typedef __attribute__((ext_vector_type(8))) short short8;
typedef __attribute__((ext_vector_type(4))) short short4v;
typedef __attribute__((ext_vector_type(4))) float f32x4;

// round-to-nearest-even f32 -> bf16 (data has no NaN)
static __device__ __forceinline__ short f2bf(float f) {
  unsigned int u = __builtin_bit_cast(unsigned int, f);
  return (short)((u + 0x7fffu + ((u >> 16) & 1u)) >> 16);
}

static __device__ __forceinline__ float fast_exp2(float x) {
#if __has_builtin(__builtin_amdgcn_exp2f)
  return __builtin_amdgcn_exp2f(x);
#else
  return exp2f(x);
#endif
}

static __device__ __forceinline__ void gload16(const void* g, void* l) {
  __builtin_amdgcn_global_load_lds(
      (const __attribute__((address_space(1))) unsigned int*)g,
      (__attribute__((address_space(3))) unsigned int*)l, 16, 0, 0);
}

__global__ __launch_bounds__(256) void cast_x_kernel(
    const float* __restrict__ in, short* __restrict__ out, int n) {
  int i = (blockIdx.x * 256 + threadIdx.x) * 4;
  if (i + 3 < n) {
    float4 v = *(const float4*)(in + i);
    short4v s;
    s[0] = f2bf(v.x); s[1] = f2bf(v.y); s[2] = f2bf(v.z); s[3] = f2bf(v.w);
    *(short4v*)(out + i) = s;
  }
}

// in [K][N] f32 row-major -> out [N][K] bf16 row-major
__global__ __launch_bounds__(256) void transpose_cast_kernel(
    const float* __restrict__ in, short* __restrict__ out, int K, int N) {
  __shared__ float tile[32][33];
  int n0 = blockIdx.x * 32, k0 = blockIdx.y * 32;
  int tx = threadIdx.x, ty = threadIdx.y;  // 32 x 8
#pragma unroll
  for (int i = 0; i < 4; ++i)
    tile[ty + i * 8][tx] = in[(size_t)(k0 + ty + i * 8) * N + (n0 + tx)];
  __syncthreads();
#pragma unroll
  for (int i = 0; i < 4; ++i)
    out[(size_t)(n0 + ty + i * 8) * K + (k0 + tx)] = f2bf(tile[tx][ty + i * 8]);
}

// C[M,N] = A[M,K](bf16) * Bt[N,K]^T(bf16) + bias. 128x128 tile, 4 waves (2x2 of 64x64).
// m97-verified structure: global_load_lds width-16 staging, 2-barrier K-loop.
// EPI 0: scatter q/k/v (q scaled 0.125; k,v XOR-swizzled; v transposed per head)
// EPI 1: fp32 output
template <int EPI>
__global__ __launch_bounds__(256, 2) void gemm128_kernel(
    const short* __restrict__ A, const short* __restrict__ Bt,
    const float* __restrict__ bias, float* __restrict__ foutp,
    short* __restrict__ q_out, short* __restrict__ k_out,
    short* __restrict__ v_out, int Mdim, int Ndim, int Kdim) {
  __shared__ __align__(16) short As[128 * 32];
  __shared__ __align__(16) short Bs[128 * 32];
  const int tid = threadIdx.x;
  const int lane = tid & 63;
  const int w = tid >> 6;
  const int wr = w >> 1, wc = w & 1;
  const int row0 = blockIdx.y * 128;
  const int col0 = blockIdx.x * 128;
  const int lrow = lane & 15, lkg = lane >> 4;

  f32x4 acc[4][4];
#pragma unroll
  for (int i = 0; i < 4; ++i)
#pragma unroll
    for (int j = 0; j < 4; ++j) acc[i][j] = (f32x4){0.f, 0.f, 0.f, 0.f};

  const short* Ab = A + (size_t)row0 * Kdim;
  const short* Bb = Bt + (size_t)col0 * Kdim;
  const int sr = tid >> 2;
  const int sc = (tid & 3) * 8;

  for (int kt = 0; kt < Kdim; kt += 32) {
    gload16(Ab + (size_t)sr * Kdim + kt + sc, As + tid * 8);
    gload16(Ab + (size_t)(sr + 64) * Kdim + kt + sc, As + 2048 + tid * 8);
    gload16(Bb + (size_t)sr * Kdim + kt + sc, Bs + tid * 8);
    gload16(Bb + (size_t)(sr + 64) * Kdim + kt + sc, Bs + 2048 + tid * 8);
    __syncthreads();
    short8 af[4], bfr[4];
#pragma unroll
    for (int i = 0; i < 4; ++i)
      af[i] = *(const short8*)(As + (wr * 64 + i * 16 + lrow) * 32 + lkg * 8);
#pragma unroll
    for (int j = 0; j < 4; ++j)
      bfr[j] = *(const short8*)(Bs + (wc * 64 + j * 16 + lrow) * 32 + lkg * 8);
#pragma unroll
    for (int i = 0; i < 4; ++i)
#pragma unroll
      for (int j = 0; j < 4; ++j)
        acc[i][j] = __builtin_amdgcn_mfma_f32_16x16x32_bf16(af[i], bfr[j], acc[i][j], 0, 0, 0);
    __syncthreads();
  }

#pragma unroll
  for (int i = 0; i < 4; ++i) {
#pragma unroll
    for (int j = 0; j < 4; ++j) {
      const int gn = col0 + wc * 64 + j * 16 + lrow;
      const int gmb = row0 + wr * 64 + i * 16 + lkg * 4;  // base row, +r<4 never crosses 2048
      float vr[4];
#pragma unroll
      for (int r = 0; r < 4; ++r) vr[r] = acc[i][j][r] + bias[gn];
      if (EPI == 0) {
        const int which = gn >> 10;
        const int hh = (gn >> 6) & 15;
        const int dd = gn & 63;
        const int b = gmb >> 11;
        const int tt0 = gmb & 2047;
        const size_t bh = (size_t)b * NHEADS + hh;
        if (which == 0) {
#pragma unroll
          for (int r = 0; r < 4; ++r)
            q_out[(bh * SEQ + tt0 + r) * HDIM + dd] = f2bf(vr[r] * 0.125f);
        } else if (which == 1) {
#pragma unroll
          for (int r = 0; r < 4; ++r)
            k_out[(bh * SEQ + tt0 + r) * HDIM + (dd ^ (((tt0 + r) & 7) << 3))] = f2bf(vr[r]);
        } else {
          // V^T: 4 consecutive tokens for fixed dim are contiguous -> one 8B store
          short4v pk;
#pragma unroll
          for (int r = 0; r < 4; ++r) pk[r] = f2bf(vr[r]);
          *(short4v*)(v_out + (bh * HDIM + dd) * SEQ + (tt0 ^ ((dd & 7) << 3))) = pk;
        }
      } else {
#pragma unroll
        for (int r = 0; r < 4; ++r)
          foutp[(size_t)(gmb + r) * Ndim + gn] = vr[r];
      }
    }
  }
}

// causal flash attention; grid (SEQ/128, B*H); 4 waves x 32 q-rows; KV tile 64
// double-buffered K/V with prefetch-before-compute; XOR-swizzled K/V/P rows
__global__ __launch_bounds__(256, 2) void attn_kernel(
    const short* __restrict__ qb, const short* __restrict__ kb,
    const short* __restrict__ vb, short* __restrict__ aout) {
  __shared__ __align__(16) short Ks2[2][64 * 64];
  __shared__ __align__(16) short Vs2[2][64 * 64];
  __shared__ __align__(16) short Ps[4 * 32 * 64];
  const int tid = threadIdx.x;
  const int lane = tid & 63;
  const int w = tid >> 6;
  const int bh = blockIdx.y;
  const int qblk = gridDim.x - 1 - blockIdx.x;  // heavy blocks launch first
  const int q0 = qblk * 128;
  const int qw0 = q0 + w * 32;
  const int lrow = lane & 15, lkg = lane >> 4;

  const short* kbase = kb + (size_t)bh * SEQ * HDIM;
  const short* vbase = vb + (size_t)bh * HDIM * SEQ;
  short* Pw = Ps + w * 2048;

  short8 qf[2][2];
#pragma unroll
  for (int rb = 0; rb < 2; ++rb) {
    const short* qrow = qb + ((size_t)bh * SEQ + qw0 + rb * 16 + lrow) * HDIM;
    qf[rb][0] = *(const short8*)(qrow + lkg * 8);
    qf[rb][1] = *(const short8*)(qrow + 32 + lkg * 8);
  }

  f32x4 o[2][4];
  float mr[2][4], lsum[2][4];
#pragma unroll
  for (int rb = 0; rb < 2; ++rb) {
#pragma unroll
    for (int g = 0; g < 4; ++g) o[rb][g] = (f32x4){0.f, 0.f, 0.f, 0.f};
#pragma unroll
    for (int r = 0; r < 4; ++r) { mr[rb][r] = -__builtin_inff(); lsum[rb][r] = 0.f; }
  }

  const int ntile = 2 * (qblk + 1);

  {  // prologue: stage tile 0 -> buf 0
    short* Kd = Ks2[0]; short* Vd = Vs2[0];
    gload16(kbase + tid * 8, Kd + tid * 8);
    gload16(kbase + 2048 + tid * 8, Kd + 2048 + tid * 8);
    gload16(vbase + (size_t)(tid >> 3) * SEQ + (tid & 7) * 8, Vd + tid * 8);
    gload16(vbase + (size_t)((tid >> 3) + 32) * SEQ + (tid & 7) * 8, Vd + 2048 + tid * 8);
  }
  __syncthreads();

  int cur = 0;
  for (int it = 0; it < ntile; ++it) {
    const int kt = it * 64;
    if (it + 1 < ntile) {  // prefetch next tile into alternate buffer
      const int k2 = kt + 64;
      short* Kd = Ks2[cur ^ 1]; short* Vd = Vs2[cur ^ 1];
      gload16(kbase + (size_t)k2 * HDIM + tid * 8, Kd + tid * 8);
      gload16(kbase + (size_t)k2 * HDIM + 2048 + tid * 8, Kd + 2048 + tid * 8);
      gload16(vbase + (size_t)(tid >> 3) * SEQ + k2 + (tid & 7) * 8, Vd + tid * 8);
      gload16(vbase + (size_t)((tid >> 3) + 32) * SEQ + k2 + (tid & 7) * 8, Vd + 2048 + tid * 8);
    }
    if (kt <= qw0 + 31) {  // wave-uniform: skip fully-masked tiles
      const short* Kc = Ks2[cur];
      const short* Vc = Vs2[cur];

      f32x4 s[2][4];
#pragma unroll
      for (int rb = 0; rb < 2; ++rb)
#pragma unroll
        for (int f = 0; f < 4; ++f) s[rb][f] = (f32x4){0.f, 0.f, 0.f, 0.f};

      __builtin_amdgcn_s_setprio(1);
#pragma unroll
      for (int c = 0; c < 2; ++c) {
#pragma unroll
        for (int f = 0; f < 4; ++f) {
          const int krow = f * 16 + lrow;
          const int kel = (c * 32 + lkg * 8) ^ ((krow & 7) << 3);
          short8 kf = *(const short8*)(Kc + krow * 64 + kel);
          s[0][f] = __builtin_amdgcn_mfma_f32_16x16x32_bf16(qf[0][c], kf, s[0][f], 0, 0, 0);
          s[1][f] = __builtin_amdgcn_mfma_f32_16x16x32_bf16(qf[1][c], kf, s[1][f], 0, 0, 0);
        }
      }
      __builtin_amdgcn_s_setprio(0);

      if (kt + 63 > qw0) {  // diagonal tile for this wave: causal mask
#pragma unroll
        for (int rb = 0; rb < 2; ++rb)
#pragma unroll
          for (int f = 0; f < 4; ++f) {
            const int kn = kt + f * 16 + lrow;
#pragma unroll
            for (int r = 0; r < 4; ++r) {
              const int qm = qw0 + rb * 16 + lkg * 4 + r;
              if (kn > qm) s[rb][f][r] = -__builtin_inff();
            }
          }
      }

      const float L2E = 1.44269504088896340736f;
#pragma unroll
      for (int rb = 0; rb < 2; ++rb) {
#pragma unroll
        for (int r = 0; r < 4; ++r) {
          float pm = fmaxf(fmaxf(s[rb][0][r], s[rb][1][r]),
                           fmaxf(s[rb][2][r], s[rb][3][r]));
          pm = fmaxf(pm, __shfl_xor(pm, 1));
          pm = fmaxf(pm, __shfl_xor(pm, 2));
          pm = fmaxf(pm, __shfl_xor(pm, 4));
          pm = fmaxf(pm, __shfl_xor(pm, 8));
          const float mn = fmaxf(mr[rb][r], pm);
          const float al = fast_exp2((mr[rb][r] - mn) * L2E);
          mr[rb][r] = mn;
          const int rl = rb * 16 + lkg * 4 + r;
          const int sw = ((lkg * 4 + r) & 7) << 3;
          float rs = 0.f;
#pragma unroll
          for (int f = 0; f < 4; ++f) {
            const float p = fast_exp2((s[rb][f][r] - mn) * L2E);
            Pw[rl * 64 + ((f * 16 + lrow) ^ sw)] = f2bf(p);
            rs += p;
          }
          rs += __shfl_xor(rs, 1);
          rs += __shfl_xor(rs, 2);
          rs += __shfl_xor(rs, 4);
          rs += __shfl_xor(rs, 8);
          lsum[rb][r] = lsum[rb][r] * al + rs;
#pragma unroll
          for (int g = 0; g < 4; ++g) o[rb][g][r] *= al;
        }
      }

      __builtin_amdgcn_s_setprio(1);
#pragma unroll
      for (int c = 0; c < 2; ++c) {
        const int pel = (c * 32 + lkg * 8) ^ ((lrow & 7) << 3);
        short8 pf0 = *(const short8*)(Pw + lrow * 64 + pel);
        short8 pf1 = *(const short8*)(Pw + (16 + lrow) * 64 + pel);
#pragma unroll
        for (int g = 0; g < 4; ++g) {
          const int vrow = g * 16 + lrow;
          const int vel = (c * 32 + lkg * 8) ^ ((vrow & 7) << 3);
          short8 vf = *(const short8*)(Vc + vrow * 64 + vel);
          o[0][g] = __builtin_amdgcn_mfma_f32_16x16x32_bf16(pf0, vf, o[0][g], 0, 0, 0);
          o[1][g] = __builtin_amdgcn_mfma_f32_16x16x32_bf16(pf1, vf, o[1][g], 0, 0, 0);
        }
      }
      __builtin_amdgcn_s_setprio(0);
    }
    __syncthreads();
    cur ^= 1;
  }

  const int b = bh >> 4, h = bh & 15;
#pragma unroll
  for (int rb = 0; rb < 2; ++rb) {
#pragma unroll
    for (int r = 0; r < 4; ++r) {
      const float inv = 1.0f / lsum[rb][r];
      const int t = qw0 + rb * 16 + lkg * 4 + r;
#pragma unroll
      for (int g = 0; g < 4; ++g)
        aout[((size_t)b * SEQ + t) * DMODEL + h * 64 + g * 16 + lrow] =
            f2bf(o[rb][g][r] * inv);
    }
  }
}

extern "C" void kernel_launch(void* const* d_in, const int* in_sizes, int n_in,
                              void* d_out, int out_size, void* d_ws, size_t ws_size,
                              hipStream_t stream) {
  const float* x = (const float*)d_in[0];
  // d_in[1] = mask (causal tril) — hardcoded in attn kernel
  const float* Wqkv = (const float*)d_in[2];
  const float* bqkv = (const float*)d_in[3];
  const float* Wout = (const float*)d_in[4];
  const float* bout = (const float*)d_in[5];

  char* ws = (char*)d_ws;
  short* xb    = (short*)(ws + 0);         // 16,777,216 B
  short* wqkvT = (short*)(ws + 16777216);  //  6,291,456 B
  short* woutT = (short*)(ws + 23068672);  //  2,097,152 B
  short* qbuf  = (short*)(ws + 25165824);  // 16,777,216 B
  short* kbuf  = (short*)(ws + 41943040);  // 16,777,216 B (row-swizzled)
  short* vbuf  = (short*)(ws + 58720256);  // 16,777,216 B (V^T per head, swizzled)
  short* abuf  = (short*)(ws + 75497472);  // 16,777,216 B — total 92,274,688 B

  cast_x_kernel<<<(MROWS * DMODEL) / 4 / 256, 256, 0, stream>>>(x, xb, MROWS * DMODEL);
  transpose_cast_kernel<<<dim3(N3 / 32, DMODEL / 32), dim3(32, 8), 0, stream>>>(
      Wqkv, wqkvT, DMODEL, N3);
  transpose_cast_kernel<<<dim3(DMODEL / 32, DMODEL / 32), dim3(32, 8), 0, stream>>>(
      Wout, woutT, DMODEL, DMODEL);
  gemm128_kernel<0><<<dim3(N3 / 128, MROWS / 128), 256, 0, stream>>>(
      xb, wqkvT, bqkv, nullptr, qbuf, kbuf, vbuf, MROWS, N3, DMODEL);
  attn_kernel<<<dim3(SEQ / 128, BHCNT), 256, 0, stream>>>(qbuf, kbuf, vbuf, abuf);
  gemm128_kernel<1><<<dim3(DMODEL / 128, MROWS / 128), 256, 0, stream>>>(
      abuf, woutT, bout, (float*)d_out, nullptr, nullptr, nullptr, MROWS, DMODEL, DMODEL);
}

// Round 5
// 309.349 us; speedup vs baseline: 1.3174x; 1.3174x over previous
//
#include <hip/hip_runtime.h>
#include <hip/hip_bf16.h>
#include <cstdint>
#include <cstddef>

#define DMODEL 1024
#define NHEADS 16
#define HDIM 64
#define BATCH 4
#define SEQ 2048
#define MROWS (BATCH*SEQ)   // 8192
#define N3 (3*DMODEL)       // 3072
#define BHCNT (BATCH*NHEADS) // 64

typedef __attribute__((ext_vector_type(8))) short short8;
typedef __attribute__((ext_vector_type(4))) short short4v;
typedef __attribute__((ext_vector_type(4))) float f32x4;
typedef __attribute__((ext_vector_type(4))) unsigned int uint4v;

// round-to-nearest-even f32 -> bf16 (data has no NaN)
static __device__ __forceinline__ short f2bf(float f) {
  unsigned int u = __builtin_bit_cast(unsigned int, f);
  return (short)((u + 0x7fffu + ((u >> 16) & 1u)) >> 16);
}

// pack two f32 -> one u32 of 2 bf16 (lo, hi) via gfx950 v_cvt_pk_bf16_f32
static __device__ __forceinline__ unsigned int pack_bf16(float lo, float hi) {
  unsigned int r;
  asm("v_cvt_pk_bf16_f32 %0, %1, %2" : "=v"(r) : "v"(lo), "v"(hi));
  return r;
}

// gfx950 fragment-transform swaps:
// permlane32_swap: a.hi32 <-> b.lo32  =>  a'={a.lo,b.lo}, b'={a.hi,b.hi}
// permlane16_swap: a.g1<->b.g0, a.g3<->b.g2 (16-lane groups)
static __device__ __forceinline__ void permlane32_swap(unsigned int& a, unsigned int& b) {
  asm("v_permlane32_swap_b32 %0, %1" : "+v"(a), "+v"(b));
}
static __device__ __forceinline__ void permlane16_swap(unsigned int& a, unsigned int& b) {
  asm("v_permlane16_swap_b32 %0, %1" : "+v"(a), "+v"(b));
}

static __device__ __forceinline__ float fast_exp2(float x) {
#if __has_builtin(__builtin_amdgcn_exp2f)
  return __builtin_amdgcn_exp2f(x);
#else
  return exp2f(x);
#endif
}

static __device__ __forceinline__ void gload16(const void* g, void* l) {
  __builtin_amdgcn_global_load_lds(
      (const __attribute__((address_space(1))) unsigned int*)g,
      (__attribute__((address_space(3))) unsigned int*)l, 16, 0, 0);
}

__global__ __launch_bounds__(256) void cast_x_kernel(
    const float* __restrict__ in, short* __restrict__ out, int n) {
  int i = (blockIdx.x * 256 + threadIdx.x) * 4;
  if (i + 3 < n) {
    float4 v = *(const float4*)(in + i);
    short4v s;
    s[0] = f2bf(v.x); s[1] = f2bf(v.y); s[2] = f2bf(v.z); s[3] = f2bf(v.w);
    *(short4v*)(out + i) = s;
  }
}

// in [K][N] f32 row-major -> out [N][K] bf16 row-major
__global__ __launch_bounds__(256) void transpose_cast_kernel(
    const float* __restrict__ in, short* __restrict__ out, int K, int N) {
  __shared__ float tile[32][33];
  int n0 = blockIdx.x * 32, k0 = blockIdx.y * 32;
  int tx = threadIdx.x, ty = threadIdx.y;  // 32 x 8
#pragma unroll
  for (int i = 0; i < 4; ++i)
    tile[ty + i * 8][tx] = in[(size_t)(k0 + ty + i * 8) * N + (n0 + tx)];
  __syncthreads();
#pragma unroll
  for (int i = 0; i < 4; ++i)
    out[(size_t)(n0 + ty + i * 8) * K + (k0 + tx)] = f2bf(tile[tx][ty + i * 8]);
}

// C[M,N] = A[M,K](bf16) * Bt[N,K]^T(bf16) + bias. 128x128 tile, 4 waves (2x2 of 64x64).
// m97-verified structure + XCD-aware block swizzle.
// EPI 0: scatter q/k/v (q scaled 0.125; k,v XOR-swizzled; v transposed per head)
// EPI 1: fp32 output
template <int EPI>
__global__ __launch_bounds__(256, 2) void gemm128_kernel(
    const short* __restrict__ A, const short* __restrict__ Bt,
    const float* __restrict__ bias, float* __restrict__ foutp,
    short* __restrict__ q_out, short* __restrict__ k_out,
    short* __restrict__ v_out, int Mdim, int Ndim, int Kdim) {
  __shared__ __align__(16) short As[128 * 32];
  __shared__ __align__(16) short Bs[128 * 32];
  const int tid = threadIdx.x;
  const int lane = tid & 63;
  const int w = tid >> 6;
  const int wr = w >> 1, wc = w & 1;
  // XCD-aware swizzle (nwg % 8 == 0 for both grids)
  const int nwg = gridDim.x * gridDim.y;
  const int lin = blockIdx.y * gridDim.x + blockIdx.x;
  const int tile = (lin & 7) * (nwg >> 3) + (lin >> 3);
  const int row0 = (tile / gridDim.x) * 128;
  const int col0 = (tile % gridDim.x) * 128;
  const int lrow = lane & 15, lkg = lane >> 4;

  f32x4 acc[4][4];
#pragma unroll
  for (int i = 0; i < 4; ++i)
#pragma unroll
    for (int j = 0; j < 4; ++j) acc[i][j] = (f32x4){0.f, 0.f, 0.f, 0.f};

  const short* Ab = A + (size_t)row0 * Kdim;
  const short* Bb = Bt + (size_t)col0 * Kdim;
  const int sr = tid >> 2;
  const int sc = (tid & 3) * 8;

  for (int kt = 0; kt < Kdim; kt += 32) {
    gload16(Ab + (size_t)sr * Kdim + kt + sc, As + tid * 8);
    gload16(Ab + (size_t)(sr + 64) * Kdim + kt + sc, As + 2048 + tid * 8);
    gload16(Bb + (size_t)sr * Kdim + kt + sc, Bs + tid * 8);
    gload16(Bb + (size_t)(sr + 64) * Kdim + kt + sc, Bs + 2048 + tid * 8);
    __syncthreads();
    short8 af[4], bfr[4];
#pragma unroll
    for (int i = 0; i < 4; ++i)
      af[i] = *(const short8*)(As + (wr * 64 + i * 16 + lrow) * 32 + lkg * 8);
#pragma unroll
    for (int j = 0; j < 4; ++j)
      bfr[j] = *(const short8*)(Bs + (wc * 64 + j * 16 + lrow) * 32 + lkg * 8);
#pragma unroll
    for (int i = 0; i < 4; ++i)
#pragma unroll
      for (int j = 0; j < 4; ++j)
        acc[i][j] = __builtin_amdgcn_mfma_f32_16x16x32_bf16(af[i], bfr[j], acc[i][j], 0, 0, 0);
    __syncthreads();
  }

#pragma unroll
  for (int i = 0; i < 4; ++i) {
#pragma unroll
    for (int j = 0; j < 4; ++j) {
      const int gn = col0 + wc * 64 + j * 16 + lrow;
      const int gmb = row0 + wr * 64 + i * 16 + lkg * 4;  // +r<4 never crosses 2048
      float vr[4];
#pragma unroll
      for (int r = 0; r < 4; ++r) vr[r] = acc[i][j][r] + bias[gn];
      if (EPI == 0) {
        const int which = gn >> 10;
        const int hh = (gn >> 6) & 15;
        const int dd = gn & 63;
        const int b = gmb >> 11;
        const int tt0 = gmb & 2047;
        const size_t bh = (size_t)b * NHEADS + hh;
        if (which == 0) {
#pragma unroll
          for (int r = 0; r < 4; ++r)
            q_out[(bh * SEQ + tt0 + r) * HDIM + dd] = f2bf(vr[r] * 0.125f);
        } else if (which == 1) {
#pragma unroll
          for (int r = 0; r < 4; ++r)
            k_out[(bh * SEQ + tt0 + r) * HDIM + (dd ^ (((tt0 + r) & 7) << 3))] = f2bf(vr[r]);
        } else {
          // V^T: 4 consecutive tokens for fixed dim -> one 8B store
          short4v pk;
#pragma unroll
          for (int r = 0; r < 4; ++r) pk[r] = f2bf(vr[r]);
          *(short4v*)(v_out + (bh * HDIM + dd) * SEQ + (tt0 ^ ((dd & 7) << 3))) = pk;
        }
      } else {
#pragma unroll
        for (int r = 0; r < 4; ++r)
          foutp[(size_t)(gmb + r) * Ndim + gn] = vr[r];
      }
    }
  }
}

// causal flash attention; 4 waves x 32 q-rows; KV tile 64; swapped QK^T:
// s = mfma(K, Q) puts a full P-row slice in-lane -> softmax reduce = 2 shfl.
// P->A-frag relayout fully in-register via cvt_pk + permlane{32,16}_swap:
//   x=q32[2c][h], y=q32[2c+1][h]; swap32(x,y); swap16(x,y)
//   => x = A-frag word (w=h), y = word (w=2+h).   (element-verified)
__global__ __launch_bounds__(256, 4) void attn_kernel(
    const short* __restrict__ qb, const short* __restrict__ kb,
    const short* __restrict__ vb, short* __restrict__ aout) {
  __shared__ __align__(16) short Ks2[2][64 * 64];
  __shared__ __align__(16) short Vs2[2][64 * 64];
  const int tid = threadIdx.x;
  const int lane = tid & 63;
  const int w = tid >> 6;
  // XCD swizzle: 1024 blocks -> each XCD gets 8 consecutive heads (K/V L2-resident)
  const int lin = blockIdx.y * gridDim.x + blockIdx.x;
  const int tile = ((lin & 7) << 7) + (lin >> 3);
  const int bh = tile >> 4;
  const int qblk = 15 - (tile & 15);  // heavy blocks first within each head
  const int q0 = qblk * 128;
  const int qw0 = q0 + w * 32;
  const int lrow = lane & 15, lkg = lane >> 4;

  const short* kbase = kb + (size_t)bh * SEQ * HDIM;
  const short* vbase = vb + (size_t)bh * HDIM * SEQ;

  short8 qf[2][2];
#pragma unroll
  for (int rb = 0; rb < 2; ++rb) {
    const short* qrow = qb + ((size_t)bh * SEQ + qw0 + rb * 16 + lrow) * HDIM;
    qf[rb][0] = *(const short8*)(qrow + lkg * 8);
    qf[rb][1] = *(const short8*)(qrow + 32 + lkg * 8);
  }

  f32x4 o[2][4];
  float mr[2], lsum[2];
#pragma unroll
  for (int rb = 0; rb < 2; ++rb) {
#pragma unroll
    for (int g = 0; g < 4; ++g) o[rb][g] = (f32x4){0.f, 0.f, 0.f, 0.f};
    mr[rb] = -__builtin_inff();
    lsum[rb] = 0.f;
  }

  const int ntile = 2 * (qblk + 1);

  {  // prologue: stage tile 0 -> buf 0
    short* Kd = Ks2[0]; short* Vd = Vs2[0];
    gload16(kbase + tid * 8, Kd + tid * 8);
    gload16(kbase + 2048 + tid * 8, Kd + 2048 + tid * 8);
    gload16(vbase + (size_t)(tid >> 3) * SEQ + (tid & 7) * 8, Vd + tid * 8);
    gload16(vbase + (size_t)((tid >> 3) + 32) * SEQ + (tid & 7) * 8, Vd + 2048 + tid * 8);
  }
  __syncthreads();

  int cur = 0;
  for (int it = 0; it < ntile; ++it) {
    const int kt = it * 64;
    if (it + 1 < ntile) {  // prefetch next tile into alternate buffer
      const int k2 = kt + 64;
      short* Kd = Ks2[cur ^ 1]; short* Vd = Vs2[cur ^ 1];
      gload16(kbase + (size_t)k2 * HDIM + tid * 8, Kd + tid * 8);
      gload16(kbase + (size_t)k2 * HDIM + 2048 + tid * 8, Kd + 2048 + tid * 8);
      gload16(vbase + (size_t)(tid >> 3) * SEQ + k2 + (tid & 7) * 8, Vd + tid * 8);
      gload16(vbase + (size_t)((tid >> 3) + 32) * SEQ + k2 + (tid & 7) * 8, Vd + 2048 + tid * 8);
    }
    if (kt <= qw0 + 31) {  // wave-uniform skip of fully-masked tiles
      const short* Kc = Ks2[cur];
      const short* Vc = Vs2[cur];

      // QK^T swapped: s[rb][f][r] = S[q = qw0+rb*16+lrow][k = kt+f*16+lkg*4+r]
      f32x4 s[2][4];
#pragma unroll
      for (int rb = 0; rb < 2; ++rb)
#pragma unroll
        for (int f = 0; f < 4; ++f) s[rb][f] = (f32x4){0.f, 0.f, 0.f, 0.f};

      __builtin_amdgcn_s_setprio(1);
#pragma unroll
      for (int c = 0; c < 2; ++c) {
#pragma unroll
        for (int f = 0; f < 4; ++f) {
          const int krow = f * 16 + lrow;
          const int kel = (c * 32 + lkg * 8) ^ ((krow & 7) << 3);
          short8 kf = *(const short8*)(Kc + krow * 64 + kel);
          s[0][f] = __builtin_amdgcn_mfma_f32_16x16x32_bf16(kf, qf[0][c], s[0][f], 0, 0, 0);
          s[1][f] = __builtin_amdgcn_mfma_f32_16x16x32_bf16(kf, qf[1][c], s[1][f], 0, 0, 0);
        }
      }
      __builtin_amdgcn_s_setprio(0);

      if (kt + 63 > qw0) {  // diagonal region: causal mask (k > q -> -inf)
#pragma unroll
        for (int rb = 0; rb < 2; ++rb) {
          const int qq = qw0 + rb * 16 + lrow;
#pragma unroll
          for (int f = 0; f < 4; ++f) {
            const int kg = kt + f * 16 + lkg * 4;
#pragma unroll
            for (int r = 0; r < 4; ++r)
              if (kg + r > qq) s[rb][f][r] = -__builtin_inff();
          }
        }
      }

      const float L2E = 1.44269504088896340736f;
      float al[2];
      unsigned int q32[2][4][2];
#pragma unroll
      for (int rb = 0; rb < 2; ++rb) {
        // in-lane max over this lane's 16 P-values of row q
        float pm = fmaxf(fmaxf(fmaxf(s[rb][0][0], s[rb][0][1]), fmaxf(s[rb][0][2], s[rb][0][3])),
                         fmaxf(fmaxf(s[rb][1][0], s[rb][1][1]), fmaxf(s[rb][1][2], s[rb][1][3])));
        pm = fmaxf(pm, fmaxf(fmaxf(fmaxf(s[rb][2][0], s[rb][2][1]), fmaxf(s[rb][2][2], s[rb][2][3])),
                             fmaxf(fmaxf(s[rb][3][0], s[rb][3][1]), fmaxf(s[rb][3][2], s[rb][3][3]))));
        pm = fmaxf(pm, __shfl_xor(pm, 16));
        pm = fmaxf(pm, __shfl_xor(pm, 32));
        const float mn = fmaxf(mr[rb], pm);
        al[rb] = fast_exp2((mr[rb] - mn) * L2E);
        mr[rb] = mn;
        float rs = 0.f;
#pragma unroll
        for (int f = 0; f < 4; ++f)
#pragma unroll
          for (int r = 0; r < 4; ++r) {
            const float p = fast_exp2((s[rb][f][r] - mn) * L2E);
            s[rb][f][r] = p;
            rs += p;
          }
        rs += __shfl_xor(rs, 16);
        rs += __shfl_xor(rs, 32);
        lsum[rb] = lsum[rb] * al[rb] + rs;
#pragma unroll
        for (int f = 0; f < 4; ++f) {
          q32[rb][f][0] = pack_bf16(s[rb][f][0], s[rb][f][1]);
          q32[rb][f][1] = pack_bf16(s[rb][f][2], s[rb][f][3]);
        }
      }

      // rescale O (alpha lives at lane lrow=q; o rows live at lkg*4+r)
#pragma unroll
      for (int r = 0; r < 4; ++r) {
        const float a0 = __shfl(al[0], lkg * 4 + r, 16);
        const float a1 = __shfl(al[1], lkg * 4 + r, 16);
#pragma unroll
        for (int g = 0; g < 4; ++g) { o[0][g][r] *= a0; o[1][g][r] *= a1; }
      }

      // O += P*V ; P A-frags assembled in-register via permlane swaps
      __builtin_amdgcn_s_setprio(1);
#pragma unroll
      for (int c = 0; c < 2; ++c) {
        uint4v pw0, pw1;
#pragma unroll
        for (int h = 0; h < 2; ++h) {
          unsigned int a0 = q32[0][2 * c][h], b0 = q32[0][2 * c + 1][h];
          permlane32_swap(a0, b0);
          permlane16_swap(a0, b0);
          pw0[h] = a0; pw0[2 + h] = b0;
          unsigned int a1 = q32[1][2 * c][h], b1 = q32[1][2 * c + 1][h];
          permlane32_swap(a1, b1);
          permlane16_swap(a1, b1);
          pw1[h] = a1; pw1[2 + h] = b1;
        }
        const short8 pf0 = __builtin_bit_cast(short8, pw0);
        const short8 pf1 = __builtin_bit_cast(short8, pw1);
#pragma unroll
        for (int g = 0; g < 4; ++g) {
          const int vrow = g * 16 + lrow;
          const int vel = (c * 32 + lkg * 8) ^ ((vrow & 7) << 3);
          short8 vf = *(const short8*)(Vc + vrow * 64 + vel);
          o[0][g] = __builtin_amdgcn_mfma_f32_16x16x32_bf16(pf0, vf, o[0][g], 0, 0, 0);
          o[1][g] = __builtin_amdgcn_mfma_f32_16x16x32_bf16(pf1, vf, o[1][g], 0, 0, 0);
        }
      }
      __builtin_amdgcn_s_setprio(0);
    }
    __syncthreads();
    cur ^= 1;
  }

  const int b = bh >> 4, h = bh & 15;
  const float li0 = 1.0f / lsum[0];
  const float li1 = 1.0f / lsum[1];
#pragma unroll
  for (int r = 0; r < 4; ++r) {
    const float i0 = __shfl(li0, lkg * 4 + r, 16);
    const float i1 = __shfl(li1, lkg * 4 + r, 16);
    const int t0 = qw0 + lkg * 4 + r;
#pragma unroll
    for (int g = 0; g < 4; ++g) {
      aout[((size_t)b * SEQ + t0) * DMODEL + h * 64 + g * 16 + lrow] = f2bf(o[0][g][r] * i0);
      aout[((size_t)b * SEQ + t0 + 16) * DMODEL + h * 64 + g * 16 + lrow] = f2bf(o[1][g][r] * i1);
    }
  }
}

extern "C" void kernel_launch(void* const* d_in, const int* in_sizes, int n_in,
                              void* d_out, int out_size, void* d_ws, size_t ws_size,
                              hipStream_t stream) {
  const float* x = (const float*)d_in[0];
  // d_in[1] = mask (causal tril) — hardcoded in attn kernel
  const float* Wqkv = (const float*)d_in[2];
  const float* bqkv = (const float*)d_in[3];
  const float* Wout = (const float*)d_in[4];
  const float* bout = (const float*)d_in[5];

  char* ws = (char*)d_ws;
  short* xb    = (short*)(ws + 0);         // 16,777,216 B
  short* wqkvT = (short*)(ws + 16777216);  //  6,291,456 B
  short* woutT = (short*)(ws + 23068672);  //  2,097,152 B
  short* qbuf  = (short*)(ws + 25165824);  // 16,777,216 B
  short* kbuf  = (short*)(ws + 41943040);  // 16,777,216 B (row-swizzled)
  short* vbuf  = (short*)(ws + 58720256);  // 16,777,216 B (V^T per head, swizzled)
  short* abuf  = (short*)(ws + 75497472);  // 16,777,216 B — total 92,274,688 B

  cast_x_kernel<<<(MROWS * DMODEL) / 4 / 256, 256, 0, stream>>>(x, xb, MROWS * DMODEL);
  transpose_cast_kernel<<<dim3(N3 / 32, DMODEL / 32), dim3(32, 8), 0, stream>>>(
      Wqkv, wqkvT, DMODEL, N3);
  transpose_cast_kernel<<<dim3(DMODEL / 32, DMODEL / 32), dim3(32, 8), 0, stream>>>(
      Wout, woutT, DMODEL, DMODEL);
  gemm128_kernel<0><<<dim3(N3 / 128, MROWS / 128), 256, 0, stream>>>(
      xb, wqkvT, bqkv, nullptr, qbuf, kbuf, vbuf, MROWS, N3, DMODEL);
  attn_kernel<<<dim3(SEQ / 128, BHCNT), 256, 0, stream>>>(qbuf, kbuf, vbuf, abuf);
  gemm128_kernel<1><<<dim3(DMODEL / 128, MROWS / 128), 256, 0, stream>>>(
      abuf, woutT, bout, (float*)d_out, nullptr, nullptr, nullptr, MROWS, DMODEL, DMODEL);
}